// Round 9
// baseline (500.215 us; speedup 1.0000x reference)
//
#include <hip/hip_runtime.h>

#define NN 100000
#define NE 1600000
#define HD 128
#define NL 3
#define NG 64
#define NC 10

#define NPART 8
#define PSZ 12500          // nodes per partition
#define NCHUNK 64
#define CSZ 25000          // edges per chunk (NE / NCHUNK)

typedef unsigned short ushortT;
typedef unsigned int uintT;

using bf16x8 = __attribute__((ext_vector_type(8))) __bf16;
using f32x4  = __attribute__((ext_vector_type(4))) float;
using f32x2  = __attribute__((ext_vector_type(2))) float;

__device__ __forceinline__ ushortT f2bf(float f) {
  unsigned int u = __float_as_uint(f);
  u += 0x7fffu + ((u >> 16) & 1u);
  return (ushortT)(u >> 16);
}
__device__ __forceinline__ float bf_lo(uintT u) { return __uint_as_float(u << 16); }
__device__ __forceinline__ float bf_hi(uintT u) { return __uint_as_float(u & 0xffff0000u); }
__device__ __forceinline__ uintT packbf2(float a, float b) {
  return (uintT)f2bf(a) | ((uintT)f2bf(b) << 16);
}

// ---------------- CSR build (LDS histogram; proven) ----------------
__global__ __launch_bounds__(256) void k_hist2(const int* __restrict__ dst, ushortT* __restrict__ hist) {
  __shared__ int cnt[PSZ];
  int tid = threadIdx.x;
  int p = blockIdx.x & 7, c = blockIdx.x >> 3;
  for (int i = tid; i < PSZ; i += 256) cnt[i] = 0;
  __syncthreads();
  int lo = p * PSZ, hi = lo + PSZ;
  const int4* d4 = (const int4*)(dst + c * CSZ);
  for (int j = tid; j < CSZ / 4; j += 256) {
    int4 v = d4[j];
    if (v.x >= lo && v.x < hi) atomicAdd(&cnt[v.x - lo], 1);
    if (v.y >= lo && v.y < hi) atomicAdd(&cnt[v.y - lo], 1);
    if (v.z >= lo && v.z < hi) atomicAdd(&cnt[v.z - lo], 1);
    if (v.w >= lo && v.w < hi) atomicAdd(&cnt[v.w - lo], 1);
  }
  __syncthreads();
  ushortT* out = hist + (size_t)(p * NCHUNK + c) * PSZ;
  for (int i = tid; i < PSZ; i += 256) out[i] = (ushortT)cnt[i];
}

__global__ __launch_bounds__(256) void k_chunkscan(const ushortT* __restrict__ hist, ushortT* __restrict__ Boff,
                                                   int* __restrict__ deg) {
  int n = blockIdx.x * 256 + threadIdx.x;
  if (n >= NN) return;
  int p = n / PSZ, i = n % PSZ;
  int s = 0;
#pragma unroll 4
  for (int c = 0; c < NCHUNK; ++c) {
    size_t idx = (size_t)(p * NCHUNK + c) * PSZ + i;
    int v = hist[idx];
    Boff[idx] = (ushortT)s;
    s += v;
  }
  deg[n] = s;
}

__global__ void k_scan1(const int* __restrict__ deg, int* __restrict__ incl, int* __restrict__ bsum) {
  __shared__ int sh[256];
  int t = threadIdx.x;
  int base = blockIdx.x * 1024 + t * 4;
  int v[4]; int s = 0;
#pragma unroll
  for (int j = 0; j < 4; ++j) { int idx = base + j; v[j] = (idx < NN) ? deg[idx] : 0; s += v[j]; }
  sh[t] = s;
  __syncthreads();
  for (int off = 1; off < 256; off <<= 1) {
    int x = (t >= off) ? sh[t - off] : 0;
    __syncthreads();
    sh[t] += x;
    __syncthreads();
  }
  int run = sh[t] - s;
#pragma unroll
  for (int j = 0; j < 4; ++j) { run += v[j]; int idx = base + j; if (idx < NN) incl[idx] = run; }
  if (t == 255) bsum[blockIdx.x] = sh[255];
}

__global__ void k_scan2(const int* __restrict__ bsum, int* __restrict__ boff, int nb) {
  if (threadIdx.x == 0 && blockIdx.x == 0) {
    int run = 0;
    for (int j = 0; j < nb; ++j) { boff[j] = run; run += bsum[j]; }
  }
}

__global__ void k_scan3(const int* __restrict__ incl, const int* __restrict__ boff,
                        int* __restrict__ row_ptr) {
  int i = blockIdx.x * 256 + threadIdx.x;
  if (i < NN) {
    row_ptr[i + 1] = boff[i >> 10] + incl[i];
    if (i == 0) row_ptr[0] = 0;
  }
}

__global__ __launch_bounds__(256) void k_scatter2(const int* __restrict__ src, const int* __restrict__ dst,
                                                  const int* __restrict__ rowp, const ushortT* __restrict__ Boff,
                                                  int* __restrict__ srt) {
  __shared__ int cur[PSZ];
  int tid = threadIdx.x;
  int p = blockIdx.x & 7, c = blockIdx.x >> 3;
  const ushortT* bo = Boff + (size_t)(p * NCHUNK + c) * PSZ;
  const int* rp = rowp + p * PSZ;
  for (int i = tid; i < PSZ; i += 256) cur[i] = rp[i] + (int)bo[i];
  __syncthreads();
  int lo = p * PSZ, hi = lo + PSZ;
  const int4* d4 = (const int4*)(dst + c * CSZ);
  const int4* s4 = (const int4*)(src + c * CSZ);
  for (int j = tid; j < CSZ / 4; j += 256) {
    int4 d = d4[j];
    int4 s = s4[j];
    if (d.x >= lo && d.x < hi) srt[atomicAdd(&cur[d.x - lo], 1)] = s.x;
    if (d.y >= lo && d.y < hi) srt[atomicAdd(&cur[d.y - lo], 1)] = s.y;
    if (d.z >= lo && d.z < hi) srt[atomicAdd(&cur[d.z - lo], 1)] = s.z;
    if (d.w >= lo && d.w < hi) srt[atomicAdd(&cur[d.w - lo], 1)] = s.w;
  }
}

// ---------------- conversions (merged: weights + features + zero sentinel row) ----------------
__global__ void k_conv(const float* __restrict__ W1, const float* __restrict__ W2,
                       ushortT* __restrict__ Wt, const float* __restrict__ x,
                       uintT* __restrict__ h) {
  int b = blockIdx.x;
  if (b < 384) {
    int idx = b * 256 + threadIdx.x;
    if (idx >= 6 * 16384) return;
    int mat = idx >> 14;
    int e = idx & 16383;
    int k = e >> 7, n = e & 127;
    int l = mat >> 1, w2 = mat & 1;
    const float* W = w2 ? W2 : W1;
    float v = W[l * 16384 + k * 128 + n];
    Wt[mat * 16384 + n * 128 + k] = f2bf(v);
  } else {
    int i = (b - 384) * 256 + threadIdx.x;
    if (i < NN * 64) {
      float2 v = ((const float2*)x)[i];
      h[i] = packbf2(v.x, v.y);
    } else if (i < NN * 64 + 64) {
      h[i] = 0u;   // zero row NN
    }
  }
}

// ---------------- aggregation (round-1 proven: one wave per node) ----------------
__global__ __launch_bounds__(256) void k_agg(const uintT* __restrict__ h, const int* __restrict__ rowp,
                                             const int* __restrict__ srt, const float* __restrict__ epsp,
                                             int l, uintT* __restrict__ z) {
  int node = blockIdx.x * 4 + (threadIdx.x >> 6);
  int lane = threadIdx.x & 63;
  int g = lane >> 4;
  int c16 = lane & 15;
  int foff = c16 << 4;
  float sc = 1.0f + epsp[l];
  const char* hb = (const char*)h;
  uint4 self = *(const uint4*)(hb + ((size_t)node << 8) + foff);
  f32x2 acc[4];
#pragma unroll
  for (int k = 0; k < 4; ++k) acc[k] = (f32x2)(0.0f);
  int e0 = rowp[node], e1 = rowp[node + 1];
  for (int base = e0; base < e1; base += 64) {
    int ii = base + lane;
    int iic = (ii < e1) ? ii : (e1 - 1);     // clamp load address in-bounds
    int idxv = (ii < e1) ? srt[iic] : NN;    // OOB slots -> zero row
    int n = e1 - base; if (n > 64) n = 64;
#pragma unroll 2
    for (int j = 0; j < n; j += 8) {
      // max src lane = 56+4+3 = 63, never wraps
      int r0 = __shfl(idxv, j + g);
      int r1 = __shfl(idxv, j + 4 + g);
      uint4 v0 = *(const uint4*)(hb + (((unsigned)r0) << 8) + foff);
      uint4 v1 = *(const uint4*)(hb + (((unsigned)r1) << 8) + foff);
      const uintT* p0 = &v0.x;
      const uintT* p1 = &v1.x;
#pragma unroll
      for (int k = 0; k < 4; ++k) {
        f32x2 t; t.x = bf_lo(p0[k]); t.y = bf_hi(p0[k]);
        acc[k] += t;
      }
#pragma unroll
      for (int k = 0; k < 4; ++k) {
        f32x2 t; t.x = bf_lo(p1[k]); t.y = bf_hi(p1[k]);
        acc[k] += t;
      }
    }
  }
  // cross-group reduce (groups differ in lane bits 4,5)
#pragma unroll
  for (int k = 0; k < 4; ++k) {
    acc[k].x += __shfl_xor(acc[k].x, 16);
    acc[k].y += __shfl_xor(acc[k].y, 16);
    acc[k].x += __shfl_xor(acc[k].x, 32);
    acc[k].y += __shfl_xor(acc[k].y, 32);
  }
  // self term
  const uintT* ps = &self.x;
#pragma unroll
  for (int k = 0; k < 4; ++k) {
    acc[k].x = fmaf(sc, bf_lo(ps[k]), acc[k].x);
    acc[k].y = fmaf(sc, bf_hi(ps[k]), acc[k].y);
  }
  if (g == 0) {
    uint4 o;
    o.x = packbf2(acc[0].x, acc[0].y);
    o.y = packbf2(acc[1].x, acc[1].y);
    o.z = packbf2(acc[2].x, acc[2].y);
    o.w = packbf2(acc[3].x, acc[3].y);
    *(uint4*)((char*)z + ((size_t)node << 8) + foff) = o;
  }
}

// ---------------- MLP v3 + entry prefetch (T14: issue-early, consume-late) ----------------
// Block = 4 waves = 64 rows; wave w owns the 16-row strip [w*16, w*16+16).
// NEW vs round 8: GEMM1 A-fragments (16B/lane) and the whole W2 matrix
// (8 uint4/thread) are loaded at kernel entry, BEFORE the Bs(W1) staging and
// its barrier — their ~500cy global latency hides under the staging instead
// of stalling GEMM1 entry and the W2 restage (which becomes pure ds_write).
// z1/output round-trip the wave's Zs strip; stores uint4-coalesced.
// last!=0: skip hout write and per-graph-reduce the block's 64 rows into
// pooled[]. LDS = 48 KB -> 3 blocks/CU (VGPR headroom ample at 12 waves/CU).
__global__ __launch_bounds__(256, 3) void k_mlp3(const ushortT* __restrict__ Z,
                                                 const ushortT* __restrict__ Wt1,
                                                 const ushortT* __restrict__ Wt2,
                                                 const float* __restrict__ b1v, const float* __restrict__ b2v,
                                                 const float* __restrict__ gammav, const float* __restrict__ betav,
                                                 const float* __restrict__ rmean, const float* __restrict__ rvar,
                                                 ushortT* __restrict__ hout,
                                                 const int* __restrict__ batch,
                                                 float* __restrict__ pooled, int last) {
  __shared__ ushortT Bs[128 * 128];  // 32 KB staged weights
  __shared__ ushortT Zs[64 * 128];   // 16 KB per-wave strips (z1, then output)
  int tid = threadIdx.x;
  int wave = tid >> 6, lane = tid & 63;
  int m0 = blockIdx.x * 64;
  int col0 = lane & 15, q = lane >> 4;
  int mA = wave * 16 + col0;

  // ---- prefetch (before any barrier): GEMM1 A-fragments + whole W2 ----
  int arow = m0 + wave * 16 + col0;
  if (arow > NN) arow = NN;           // rows >= NN clamp to zero-sentinel row NN
  const ushortT* zrow = Z + (size_t)arow * 128;
  bf16x8 a[4];
#pragma unroll
  for (int kk = 0; kk < 4; ++kk) a[kk] = *(const bf16x8*)(zrow + (kk * 4 + q) * 8);
  uint4 w2p[8];
#pragma unroll
  for (int it = 0; it < 8; ++it) w2p[it] = *(const uint4*)(Wt2 + (it * 256 + tid) * 8);

  // stage Bs = W1
#pragma unroll
  for (int it = 0; it < 8; ++it) {
    int c = it * 256 + tid;
    int n = c >> 4, c8 = c & 15;
    uint4 v = *(const uint4*)(Wt1 + n * 128 + c8 * 8);
    *(uint4*)(&Bs[(n * 16 + (c8 ^ (n & 15))) * 8]) = v;
  }
  __syncthreads();

  // ---- GEMM1: A from registers ----
  f32x4 acc[8];
#pragma unroll
  for (int t = 0; t < 8; ++t) acc[t] = (f32x4)(0.0f);
#pragma unroll
  for (int kk = 0; kk < 4; ++kk) {
    int kc = kk * 4 + q;
#pragma unroll
    for (int t = 0; t < 8; ++t) {
      int n = t * 16 + col0;
      bf16x8 b = *(const bf16x8*)(&Bs[(n * 16 + (kc ^ (n & 15))) * 8]);
      acc[t] = __builtin_amdgcn_mfma_f32_16x16x32_bf16(a[kk], b, acc[t], 0, 0, 0);
    }
  }

  // ---- epilogue1: Zs_strip = relu(acc + b1) (own strip only, no barrier needed) ----
#pragma unroll
  for (int t = 0; t < 8; ++t) {
    int n = t * 16 + col0;
    float bi = b1v[n];
#pragma unroll
    for (int r = 0; r < 4; ++r) {
      int row = wave * 16 + q * 4 + r;
      float v = fmaxf(acc[t][r] + bi, 0.0f);
      Zs[(row * 16 + ((n >> 3) ^ (row & 15))) * 8 + (n & 7)] = f2bf(v);
    }
  }
  __syncthreads();   // all waves done reading Bs(W1)

  // restage Bs = W2 from registers (pure ds_write, no global latency)
#pragma unroll
  for (int it = 0; it < 8; ++it) {
    int c = it * 256 + tid;
    int n = c >> 4, c8 = c & 15;
    *(uint4*)(&Bs[(n * 16 + (c8 ^ (n & 15))) * 8]) = w2p[it];
  }
  __syncthreads();

  // ---- GEMM2: A from own Zs strip ----
#pragma unroll
  for (int t = 0; t < 8; ++t) acc[t] = (f32x4)(0.0f);
#pragma unroll
  for (int kk = 0; kk < 4; ++kk) {
    int kc = kk * 4 + q;
    bf16x8 a0 = *(const bf16x8*)(&Zs[(mA * 16 + (kc ^ (mA & 15))) * 8]);
#pragma unroll
    for (int t = 0; t < 8; ++t) {
      int n = t * 16 + col0;
      bf16x8 b = *(const bf16x8*)(&Bs[(n * 16 + (kc ^ (n & 15))) * 8]);
      acc[t] = __builtin_amdgcn_mfma_f32_16x16x32_bf16(a0, b, acc[t], 0, 0, 0);
    }
  }

  // ---- epilogue2: Zs_strip = relu(BN(relu(acc + b2))) ----
#pragma unroll
  for (int t = 0; t < 8; ++t) {
    int n = t * 16 + col0;
    float bi = b2v[n];
    float scn = gammav[n] * rsqrtf(rvar[n] + 1e-5f);
    float o = betav[n] - rmean[n] * scn;
#pragma unroll
    for (int r = 0; r < 4; ++r) {
      int row = wave * 16 + q * 4 + r;
      float v = fmaxf(acc[t][r] + bi, 0.0f);
      v = fmaxf(fmaf(v, scn, o), 0.0f);
      Zs[(row * 16 + ((n >> 3) ^ (row & 15))) * 8 + (n & 7)] = f2bf(v);
    }
  }

  if (!last) {
    // coalesced uint4 store of the wave's strip (same-wave LDS ordering)
#pragma unroll
    for (int it = 0; it < 4; ++it) {
      int c = it * 64 + lane;
      int r = c >> 4, c8 = c & 15;
      int row = wave * 16 + r;
      int gm = m0 + row;
      if (gm < NN) {
        uint4 v = *(const uint4*)(&Zs[(row * 16 + (c8 ^ (row & 15))) * 8]);
        *(uint4*)(hout + (size_t)gm * 128 + c8 * 8) = v;
      }
    }
  } else {
    // fused global_add_pool: reduce the block's 64 rows per graph into pooled
    __syncthreads();   // cross-wave Zs reads below
    int f = tid & 127;
    int half = tid >> 7;          // 0: rows 0..31, 1: rows 32..63
    float a2 = 0.0f;
    int curg = -1;
    for (int r = 0; r < 32; ++r) {
      int row = half * 32 + r;
      int gm = m0 + row;
      if (gm >= NN) break;
      int gr = batch[gm];
      if (gr != curg) {
        if (curg >= 0) atomicAdd(&pooled[curg * 128 + f], a2);
        curg = gr; a2 = 0.0f;
      }
      ushortT v = Zs[(row * 16 + ((f >> 3) ^ (row & 15))) * 8 + (f & 7)];
      a2 += __uint_as_float(((uintT)v) << 16);
    }
    if (curg >= 0) atomicAdd(&pooled[curg * 128 + f], a2);
  }
}

// ---------------- head ----------------
__global__ __launch_bounds__(128) void k_head(const float* __restrict__ pooled,
                                              const float* __restrict__ w1, const float* __restrict__ b1,
                                              const float* __restrict__ w2, const float* __restrict__ b2,
                                              const float* __restrict__ w3, const float* __restrict__ b3,
                                              float* __restrict__ out) {
  __shared__ float p[128], y1[128], y2[64], lg[NC], lse;
  int g = blockIdx.x, t = threadIdx.x;
  p[t] = pooled[g * 128 + t];
  __syncthreads();
  float acc = b1[t];
  for (int k = 0; k < 128; ++k) acc = fmaf(p[k], w1[k * 128 + t], acc);
  y1[t] = fmaxf(acc, 0.0f);
  __syncthreads();
  if (t < 64) {
    float a = b2[t];
    for (int k = 0; k < 128; ++k) a = fmaf(y1[k], w2[k * 64 + t], a);
    y2[t] = fmaxf(a, 0.0f);
  }
  __syncthreads();
  if (t < NC) {
    float a = b3[t];
    for (int k = 0; k < 64; ++k) a = fmaf(y2[k], w3[k * NC + t], a);
    lg[t] = a;
  }
  __syncthreads();
  if (t == 0) {
    float m = -1e30f;
    for (int j = 0; j < NC; ++j) m = fmaxf(m, lg[j]);
    float sum = 0.0f;
    for (int j = 0; j < NC; ++j) sum += expf(lg[j] - m);
    lse = m + logf(sum);
  }
  __syncthreads();
  if (t < NC) out[g * NC + t] = lg[t] - lse;
}

// ---------------- launch ----------------
extern "C" void kernel_launch(void* const* d_in, const int* in_sizes, int n_in,
                              void* d_out, int out_size, void* d_ws, size_t ws_size,
                              hipStream_t stream) {
  const float* x     = (const float*)d_in[0];
  const int*   ei    = (const int*)d_in[1];
  const int*   srcp  = ei;
  const int*   dstp  = ei + NE;
  const int*   batch = (const int*)d_in[2];
  const float* eps   = (const float*)d_in[3];
  const float* W1    = (const float*)d_in[4];
  const float* b1    = (const float*)d_in[5];
  const float* W2    = (const float*)d_in[6];
  const float* b2    = (const float*)d_in[7];
  const float* gam   = (const float*)d_in[8];
  const float* bet   = (const float*)d_in[9];
  const float* rm    = (const float*)d_in[10];
  const float* rv    = (const float*)d_in[11];
  const float* fc1w  = (const float*)d_in[12];
  const float* fc1b  = (const float*)d_in[13];
  const float* fc2w  = (const float*)d_in[14];
  const float* fc2b  = (const float*)d_in[15];
  const float* fc3w  = (const float*)d_in[16];
  const float* fc3b  = (const float*)d_in[17];
  float* out = (float*)d_out;

  char* w = (char*)d_ws;
  uintT* bufA   = (uintT*)w;               w += ((size_t)NN * 64 + 64) * 4; // 25.6 MB + zero row
  uintT* bufB   = (uintT*)w;               w += ((size_t)NN * 64 + 64) * 4; // 25.6 MB + zero row
  int*   srt    = (int*)w;                 w += (size_t)NE * 4;             // 6.4 MB
  int*   rowp   = (int*)w;                 w += 400128;
  int*   deg    = (int*)w;                 w += 400128;
  int*   incl   = (int*)w;                 w += 400128;
  int*   bsum   = (int*)w;                 w += 2048;
  int*   boff   = (int*)w;                 w += 2048;
  ushortT* Wt   = (ushortT*)w;             w += 6 * 16384 * 2;
  float* pooled = (float*)w;               w += NG * HD * 4;

  // hist/Boff alias bufA/bufB (dead before conversions run): 8*64*12500*2 = 12.8 MB each
  ushortT* hist = (ushortT*)bufA;
  ushortT* Boff = (ushortT*)bufB;

  hipMemsetAsync(pooled, 0, (size_t)NG * HD * 4, stream);
  // zero sentinel row NN of bufB (bufA's is written by k_conv); beyond Boff's
  // 12.8 MB alias region, so order vs CSR build doesn't matter.
  hipMemsetAsync((char*)bufB + (size_t)NN * 256, 0, 256, stream);

  k_hist2<<<dim3(NPART * NCHUNK), dim3(256), 0, stream>>>(dstp, hist);
  k_chunkscan<<<dim3((NN + 255) / 256), dim3(256), 0, stream>>>(hist, Boff, deg);
  int nb = (NN + 1023) / 1024;
  k_scan1<<<dim3(nb), dim3(256), 0, stream>>>(deg, incl, bsum);
  k_scan2<<<dim3(1), dim3(64), 0, stream>>>(bsum, boff, nb);
  k_scan3<<<dim3((NN + 255) / 256), dim3(256), 0, stream>>>(incl, boff, rowp);
  k_scatter2<<<dim3(NPART * NCHUNK), dim3(256), 0, stream>>>(srcp, dstp, rowp, Boff, srt);

  k_conv<<<dim3(384 + NN * 64 / 256 + 1), dim3(256), 0, stream>>>(W1, W2, Wt, x, bufA);

  // h lives in bufA across layers; z in bufB (row NN of both = zero sentinel)
  int mgrid = (NN + 63) / 64;  // 1563
  for (int l = 0; l < NL; ++l) {
    k_agg<<<dim3(NN / 4), dim3(256), 0, stream>>>(bufA, rowp, srt, eps, l, bufB);
    k_mlp3<<<dim3(mgrid), dim3(256), 0, stream>>>((const ushortT*)bufB,
                                                  Wt + (2 * l) * 16384, Wt + (2 * l + 1) * 16384,
                                                  b1 + l * 128, b2 + l * 128,
                                                  gam + l * 128, bet + l * 128,
                                                  rm + l * 128, rv + l * 128,
                                                  (ushortT*)bufA,
                                                  batch, pooled, (l == NL - 1) ? 1 : 0);
  }

  k_head<<<dim3(NG), dim3(128), 0, stream>>>(pooled, fc1w, fc1b, fc2w, fc2b, fc3w, fc3b, out);
}

// Round 11
// 458.428 us; speedup vs baseline: 1.0912x; 1.0912x over previous
//
#include <hip/hip_runtime.h>

#define NN 100000
#define NE 1600000
#define HD 128
#define NL 3
#define NG 64
#define NC 10

#define NPART 8
#define PSZ 12500          // nodes per partition
#define NCHUNK 64
#define CSZ 25000          // edges per chunk (NE / NCHUNK)

typedef unsigned short ushortT;
typedef unsigned int uintT;

using bf16x8 = __attribute__((ext_vector_type(8))) __bf16;
using f32x4  = __attribute__((ext_vector_type(4))) float;
using f32x2  = __attribute__((ext_vector_type(2))) float;

__device__ __forceinline__ ushortT f2bf(float f) {
  unsigned int u = __float_as_uint(f);
  u += 0x7fffu + ((u >> 16) & 1u);
  return (ushortT)(u >> 16);
}
__device__ __forceinline__ float bf_lo(uintT u) { return __uint_as_float(u << 16); }
__device__ __forceinline__ float bf_hi(uintT u) { return __uint_as_float(u & 0xffff0000u); }
__device__ __forceinline__ uintT packbf2(float a, float b) {
  return (uintT)f2bf(a) | ((uintT)f2bf(b) << 16);
}

// ---------------- CSR build (LDS histogram, 50 KB/wg; proven in 460us run) ----------------
__global__ __launch_bounds__(256) void k_hist2(const int* __restrict__ dst, ushortT* __restrict__ hist) {
  __shared__ int cnt[PSZ];
  int tid = threadIdx.x;
  int p = blockIdx.x & 7, c = blockIdx.x >> 3;
  for (int i = tid; i < PSZ; i += 256) cnt[i] = 0;
  __syncthreads();
  int lo = p * PSZ, hi = lo + PSZ;
  const int4* d4 = (const int4*)(dst + c * CSZ);
  for (int j = tid; j < CSZ / 4; j += 256) {
    int4 v = d4[j];
    if (v.x >= lo && v.x < hi) atomicAdd(&cnt[v.x - lo], 1);
    if (v.y >= lo && v.y < hi) atomicAdd(&cnt[v.y - lo], 1);
    if (v.z >= lo && v.z < hi) atomicAdd(&cnt[v.z - lo], 1);
    if (v.w >= lo && v.w < hi) atomicAdd(&cnt[v.w - lo], 1);
  }
  __syncthreads();
  ushortT* out = hist + (size_t)(p * NCHUNK + c) * PSZ;
  for (int i = tid; i < PSZ; i += 256) out[i] = (ushortT)cnt[i];
}

__global__ __launch_bounds__(256) void k_chunkscan(const ushortT* __restrict__ hist, ushortT* __restrict__ Boff,
                                                   int* __restrict__ deg) {
  int n = blockIdx.x * 256 + threadIdx.x;
  if (n >= NN) return;
  int p = n / PSZ, i = n % PSZ;
  int s = 0;
#pragma unroll 4
  for (int c = 0; c < NCHUNK; ++c) {
    size_t idx = (size_t)(p * NCHUNK + c) * PSZ + i;
    int v = hist[idx];
    Boff[idx] = (ushortT)s;
    s += v;
  }
  deg[n] = s;
}

__global__ void k_scan1(const int* __restrict__ deg, int* __restrict__ incl, int* __restrict__ bsum) {
  __shared__ int sh[256];
  int t = threadIdx.x;
  int base = blockIdx.x * 1024 + t * 4;
  int v[4]; int s = 0;
#pragma unroll
  for (int j = 0; j < 4; ++j) { int idx = base + j; v[j] = (idx < NN) ? deg[idx] : 0; s += v[j]; }
  sh[t] = s;
  __syncthreads();
  for (int off = 1; off < 256; off <<= 1) {
    int x = (t >= off) ? sh[t - off] : 0;
    __syncthreads();
    sh[t] += x;
    __syncthreads();
  }
  int run = sh[t] - s;
#pragma unroll
  for (int j = 0; j < 4; ++j) { run += v[j]; int idx = base + j; if (idx < NN) incl[idx] = run; }
  if (t == 255) bsum[blockIdx.x] = sh[255];
}

__global__ void k_scan2(const int* __restrict__ bsum, int* __restrict__ boff, int nb) {
  if (threadIdx.x == 0 && blockIdx.x == 0) {
    int run = 0;
    for (int j = 0; j < nb; ++j) { boff[j] = run; run += bsum[j]; }
  }
}

__global__ void k_scan3(const int* __restrict__ incl, const int* __restrict__ boff,
                        int* __restrict__ row_ptr) {
  int i = blockIdx.x * 256 + threadIdx.x;
  if (i < NN) {
    row_ptr[i + 1] = boff[i >> 10] + incl[i];
    if (i == 0) row_ptr[0] = 0;
  }
}

__global__ __launch_bounds__(256) void k_scatter2(const int* __restrict__ src, const int* __restrict__ dst,
                                                  const int* __restrict__ rowp, const ushortT* __restrict__ Boff,
                                                  int* __restrict__ srt) {
  __shared__ int cur[PSZ];
  int tid = threadIdx.x;
  int p = blockIdx.x & 7, c = blockIdx.x >> 3;
  const ushortT* bo = Boff + (size_t)(p * NCHUNK + c) * PSZ;
  const int* rp = rowp + p * PSZ;
  for (int i = tid; i < PSZ; i += 256) cur[i] = rp[i] + (int)bo[i];
  __syncthreads();
  int lo = p * PSZ, hi = lo + PSZ;
  const int4* d4 = (const int4*)(dst + c * CSZ);
  const int4* s4 = (const int4*)(src + c * CSZ);
  for (int j = tid; j < CSZ / 4; j += 256) {
    int4 d = d4[j];
    int4 s = s4[j];
    if (d.x >= lo && d.x < hi) srt[atomicAdd(&cur[d.x - lo], 1)] = s.x;
    if (d.y >= lo && d.y < hi) srt[atomicAdd(&cur[d.y - lo], 1)] = s.y;
    if (d.z >= lo && d.z < hi) srt[atomicAdd(&cur[d.z - lo], 1)] = s.z;
    if (d.w >= lo && d.w < hi) srt[atomicAdd(&cur[d.w - lo], 1)] = s.w;
  }
}

// ---------------- conversions (merged: weights + features + zero sentinel row) ----------------
__global__ void k_conv(const float* __restrict__ W1, const float* __restrict__ W2,
                       ushortT* __restrict__ Wt, const float* __restrict__ x,
                       uintT* __restrict__ h) {
  int b = blockIdx.x;
  if (b < 384) {
    int idx = b * 256 + threadIdx.x;
    if (idx >= 6 * 16384) return;
    int mat = idx >> 14;
    int e = idx & 16383;
    int k = e >> 7, n = e & 127;
    int l = mat >> 1, w2 = mat & 1;
    const float* W = w2 ? W2 : W1;
    float v = W[l * 16384 + k * 128 + n];
    Wt[mat * 16384 + n * 128 + k] = f2bf(v);
  } else {
    int i = (b - 384) * 256 + threadIdx.x;
    if (i < NN * 64) {
      float2 v = ((const float2*)x)[i];
      h[i] = packbf2(v.x, v.y);
    } else if (i < NN * 64 + 64) {
      h[i] = 0u;   // zero row NN
    }
  }
}

// ---------------- aggregation (round-1 proven; explicit 8 blocks/CU occupancy hint) ----------------
__global__ __launch_bounds__(256, 8) void k_agg(const uintT* __restrict__ h, const int* __restrict__ rowp,
                                                const int* __restrict__ srt, const float* __restrict__ epsp,
                                                int l, uintT* __restrict__ z) {
  int node = blockIdx.x * 4 + (threadIdx.x >> 6);
  int lane = threadIdx.x & 63;
  int g = lane >> 4;
  int c16 = lane & 15;
  int foff = c16 << 4;
  float sc = 1.0f + epsp[l];
  const char* hb = (const char*)h;
  uint4 self = *(const uint4*)(hb + ((size_t)node << 8) + foff);
  f32x2 acc[4];
#pragma unroll
  for (int k = 0; k < 4; ++k) acc[k] = (f32x2)(0.0f);
  int e0 = rowp[node], e1 = rowp[node + 1];
  for (int base = e0; base < e1; base += 64) {
    int ii = base + lane;
    int iic = (ii < e1) ? ii : (e1 - 1);     // clamp load address in-bounds
    int idxv = (ii < e1) ? srt[iic] : NN;    // OOB slots -> zero row
    int n = e1 - base; if (n > 64) n = 64;
#pragma unroll 2
    for (int j = 0; j < n; j += 8) {
      // max src lane = 56+4+3 = 63, never wraps
      int r0 = __shfl(idxv, j + g);
      int r1 = __shfl(idxv, j + 4 + g);
      uint4 v0 = *(const uint4*)(hb + (((unsigned)r0) << 8) + foff);
      uint4 v1 = *(const uint4*)(hb + (((unsigned)r1) << 8) + foff);
      const uintT* p0 = &v0.x;
      const uintT* p1 = &v1.x;
#pragma unroll
      for (int k = 0; k < 4; ++k) {
        f32x2 t; t.x = bf_lo(p0[k]); t.y = bf_hi(p0[k]);
        acc[k] += t;
      }
#pragma unroll
      for (int k = 0; k < 4; ++k) {
        f32x2 t; t.x = bf_lo(p1[k]); t.y = bf_hi(p1[k]);
        acc[k] += t;
      }
    }
  }
  // cross-group reduce (groups differ in lane bits 4,5)
#pragma unroll
  for (int k = 0; k < 4; ++k) {
    acc[k].x += __shfl_xor(acc[k].x, 16);
    acc[k].y += __shfl_xor(acc[k].y, 16);
    acc[k].x += __shfl_xor(acc[k].x, 32);
    acc[k].y += __shfl_xor(acc[k].y, 32);
  }
  // self term
  const uintT* ps = &self.x;
#pragma unroll
  for (int k = 0; k < 4; ++k) {
    acc[k].x = fmaf(sc, bf_lo(ps[k]), acc[k].x);
    acc[k].y = fmaf(sc, bf_hi(ps[k]), acc[k].y);
  }
  if (g == 0) {
    uint4 o;
    o.x = packbf2(acc[0].x, acc[0].y);
    o.y = packbf2(acc[1].x, acc[1].y);
    o.z = packbf2(acc[2].x, acc[2].y);
    o.w = packbf2(acc[3].x, acc[3].y);
    *(uint4*)((char*)z + ((size_t)node << 8) + foff) = o;
  }
}

// ---------------- MLP v3 (round-8 proven) + fused global_add_pool on last layer ----------------
// Block = 4 waves = 64 rows; wave w owns the 16-row strip [w*16, w*16+16).
// GEMM1 A direct from global Z; B staged in 32 KB Bs (W2 restaged after
// barrier); z1/output round-trip the wave's Zs strip; stores uint4-coalesced.
// last!=0: skip hout write and per-graph-reduce the block's 64 rows into
// pooled[]. LDS = 48 KB -> 3 blocks/CU. (Entry-prefetch variant measured
// -13us/layer in round 9 -- do not reintroduce.)
__global__ __launch_bounds__(256, 3) void k_mlp3(const ushortT* __restrict__ Z,
                                                 const ushortT* __restrict__ Wt1,
                                                 const ushortT* __restrict__ Wt2,
                                                 const float* __restrict__ b1v, const float* __restrict__ b2v,
                                                 const float* __restrict__ gammav, const float* __restrict__ betav,
                                                 const float* __restrict__ rmean, const float* __restrict__ rvar,
                                                 ushortT* __restrict__ hout,
                                                 const int* __restrict__ batch,
                                                 float* __restrict__ pooled, int last) {
  __shared__ ushortT Bs[128 * 128];  // 32 KB staged weights
  __shared__ ushortT Zs[64 * 128];   // 16 KB per-wave strips (z1, then output)
  int tid = threadIdx.x;
  int wave = tid >> 6, lane = tid & 63;
  int m0 = blockIdx.x * 64;
  int col0 = lane & 15, q = lane >> 4;
  int mA = wave * 16 + col0;

  // stage Bs = W1
#pragma unroll
  for (int it = 0; it < 8; ++it) {
    int c = it * 256 + tid;
    int n = c >> 4, c8 = c & 15;
    uint4 v = *(const uint4*)(Wt1 + n * 128 + c8 * 8);
    *(uint4*)(&Bs[(n * 16 + (c8 ^ (n & 15))) * 8]) = v;
  }
  __syncthreads();

  // ---- GEMM1: A direct from global Z (rows >= NN clamp to zero-sentinel row NN) ----
  int arow = m0 + wave * 16 + col0;
  if (arow > NN) arow = NN;
  const ushortT* zrow = Z + (size_t)arow * 128;
  f32x4 acc[8];
#pragma unroll
  for (int t = 0; t < 8; ++t) acc[t] = (f32x4)(0.0f);
#pragma unroll
  for (int kk = 0; kk < 4; ++kk) {
    int kc = kk * 4 + q;
    bf16x8 a0 = *(const bf16x8*)(zrow + kc * 8);
#pragma unroll
    for (int t = 0; t < 8; ++t) {
      int n = t * 16 + col0;
      bf16x8 b = *(const bf16x8*)(&Bs[(n * 16 + (kc ^ (n & 15))) * 8]);
      acc[t] = __builtin_amdgcn_mfma_f32_16x16x32_bf16(a0, b, acc[t], 0, 0, 0);
    }
  }

  // ---- epilogue1: Zs_strip = relu(acc + b1) (own strip only, no barrier needed) ----
#pragma unroll
  for (int t = 0; t < 8; ++t) {
    int n = t * 16 + col0;
    float bi = b1v[n];
#pragma unroll
    for (int r = 0; r < 4; ++r) {
      int row = wave * 16 + q * 4 + r;
      float v = fmaxf(acc[t][r] + bi, 0.0f);
      Zs[(row * 16 + ((n >> 3) ^ (row & 15))) * 8 + (n & 7)] = f2bf(v);
    }
  }
  __syncthreads();   // all waves done reading Bs(W1)

  // restage Bs = W2
#pragma unroll
  for (int it = 0; it < 8; ++it) {
    int c = it * 256 + tid;
    int n = c >> 4, c8 = c & 15;
    uint4 v = *(const uint4*)(Wt2 + n * 128 + c8 * 8);
    *(uint4*)(&Bs[(n * 16 + (c8 ^ (n & 15))) * 8]) = v;
  }
  __syncthreads();

  // ---- GEMM2: A from own Zs strip ----
#pragma unroll
  for (int t = 0; t < 8; ++t) acc[t] = (f32x4)(0.0f);
#pragma unroll
  for (int kk = 0; kk < 4; ++kk) {
    int kc = kk * 4 + q;
    bf16x8 a0 = *(const bf16x8*)(&Zs[(mA * 16 + (kc ^ (mA & 15))) * 8]);
#pragma unroll
    for (int t = 0; t < 8; ++t) {
      int n = t * 16 + col0;
      bf16x8 b = *(const bf16x8*)(&Bs[(n * 16 + (kc ^ (n & 15))) * 8]);
      acc[t] = __builtin_amdgcn_mfma_f32_16x16x32_bf16(a0, b, acc[t], 0, 0, 0);
    }
  }

  // ---- epilogue2: Zs_strip = relu(BN(relu(acc + b2))) ----
#pragma unroll
  for (int t = 0; t < 8; ++t) {
    int n = t * 16 + col0;
    float bi = b2v[n];
    float scn = gammav[n] * rsqrtf(rvar[n] + 1e-5f);
    float o = betav[n] - rmean[n] * scn;
#pragma unroll
    for (int r = 0; r < 4; ++r) {
      int row = wave * 16 + q * 4 + r;
      float v = fmaxf(acc[t][r] + bi, 0.0f);
      v = fmaxf(fmaf(v, scn, o), 0.0f);
      Zs[(row * 16 + ((n >> 3) ^ (row & 15))) * 8 + (n & 7)] = f2bf(v);
    }
  }

  if (!last) {
    // coalesced uint4 store of the wave's strip (same-wave LDS ordering)
#pragma unroll
    for (int it = 0; it < 4; ++it) {
      int c = it * 64 + lane;
      int r = c >> 4, c8 = c & 15;
      int row = wave * 16 + r;
      int gm = m0 + row;
      if (gm < NN) {
        uint4 v = *(const uint4*)(&Zs[(row * 16 + (c8 ^ (row & 15))) * 8]);
        *(uint4*)(hout + (size_t)gm * 128 + c8 * 8) = v;
      }
    }
  } else {
    // fused global_add_pool: reduce the block's 64 rows per graph into pooled
    __syncthreads();   // cross-wave Zs reads below
    int f = tid & 127;
    int half = tid >> 7;          // 0: rows 0..31, 1: rows 32..63
    float a2 = 0.0f;
    int curg = -1;
    for (int r = 0; r < 32; ++r) {
      int row = half * 32 + r;
      int gm = m0 + row;
      if (gm >= NN) break;
      int gr = batch[gm];
      if (gr != curg) {
        if (curg >= 0) atomicAdd(&pooled[curg * 128 + f], a2);
        curg = gr; a2 = 0.0f;
      }
      ushortT v = Zs[(row * 16 + ((f >> 3) ^ (row & 15))) * 8 + (f & 7)];
      a2 += __uint_as_float(((uintT)v) << 16);
    }
    if (curg >= 0) atomicAdd(&pooled[curg * 128 + f], a2);
  }
}

// ---------------- head ----------------
__global__ __launch_bounds__(128) void k_head(const float* __restrict__ pooled,
                                              const float* __restrict__ w1, const float* __restrict__ b1,
                                              const float* __restrict__ w2, const float* __restrict__ b2,
                                              const float* __restrict__ w3, const float* __restrict__ b3,
                                              float* __restrict__ out) {
  __shared__ float p[128], y1[128], y2[64], lg[NC], lse;
  int g = blockIdx.x, t = threadIdx.x;
  p[t] = pooled[g * 128 + t];
  __syncthreads();
  float acc = b1[t];
  for (int k = 0; k < 128; ++k) acc = fmaf(p[k], w1[k * 128 + t], acc);
  y1[t] = fmaxf(acc, 0.0f);
  __syncthreads();
  if (t < 64) {
    float a = b2[t];
    for (int k = 0; k < 128; ++k) a = fmaf(y1[k], w2[k * 64 + t], a);
    y2[t] = fmaxf(a, 0.0f);
  }
  __syncthreads();
  if (t < NC) {
    float a = b3[t];
    for (int k = 0; k < 64; ++k) a = fmaf(y2[k], w3[k * NC + t], a);
    lg[t] = a;
  }
  __syncthreads();
  if (t == 0) {
    float m = -1e30f;
    for (int j = 0; j < NC; ++j) m = fmaxf(m, lg[j]);
    float sum = 0.0f;
    for (int j = 0; j < NC; ++j) sum += expf(lg[j] - m);
    lse = m + logf(sum);
  }
  __syncthreads();
  if (t < NC) out[g * NC + t] = lg[t] - lse;
}

// ---------------- launch ----------------
extern "C" void kernel_launch(void* const* d_in, const int* in_sizes, int n_in,
                              void* d_out, int out_size, void* d_ws, size_t ws_size,
                              hipStream_t stream) {
  const float* x     = (const float*)d_in[0];
  const int*   ei    = (const int*)d_in[1];
  const int*   srcp  = ei;
  const int*   dstp  = ei + NE;
  const int*   batch = (const int*)d_in[2];
  const float* eps   = (const float*)d_in[3];
  const float* W1    = (const float*)d_in[4];
  const float* b1    = (const float*)d_in[5];
  const float* W2    = (const float*)d_in[6];
  const float* b2    = (const float*)d_in[7];
  const float* gam   = (const float*)d_in[8];
  const float* bet   = (const float*)d_in[9];
  const float* rm    = (const float*)d_in[10];
  const float* rv    = (const float*)d_in[11];
  const float* fc1w  = (const float*)d_in[12];
  const float* fc1b  = (const float*)d_in[13];
  const float* fc2w  = (const float*)d_in[14];
  const float* fc2b  = (const float*)d_in[15];
  const float* fc3w  = (const float*)d_in[16];
  const float* fc3b  = (const float*)d_in[17];
  float* out = (float*)d_out;

  char* w = (char*)d_ws;
  uintT* bufA   = (uintT*)w;               w += ((size_t)NN * 64 + 64) * 4; // 25.6 MB + zero row
  uintT* bufB   = (uintT*)w;               w += ((size_t)NN * 64 + 64) * 4; // 25.6 MB + zero row
  int*   srt    = (int*)w;                 w += (size_t)NE * 4;             // 6.4 MB
  int*   rowp   = (int*)w;                 w += 400128;
  int*   deg    = (int*)w;                 w += 400128;
  int*   incl   = (int*)w;                 w += 400128;
  int*   bsum   = (int*)w;                 w += 2048;
  int*   boff   = (int*)w;                 w += 2048;
  ushortT* Wt   = (ushortT*)w;             w += 6 * 16384 * 2;
  float* pooled = (float*)w;               w += NG * HD * 4;

  // hist/Boff alias bufA/bufB (dead before conversions run): 8*64*12500*2 = 12.8 MB each
  ushortT* hist = (ushortT*)bufA;
  ushortT* Boff = (ushortT*)bufB;

  hipMemsetAsync(pooled, 0, (size_t)NG * HD * 4, stream);
  // zero sentinel row NN of bufB (bufA's is written by k_conv); beyond Boff's
  // 12.8 MB alias region, so order vs CSR build doesn't matter.
  hipMemsetAsync((char*)bufB + (size_t)NN * 256, 0, 256, stream);

  k_hist2<<<dim3(NPART * NCHUNK), dim3(256), 0, stream>>>(dstp, hist);
  k_chunkscan<<<dim3((NN + 255) / 256), dim3(256), 0, stream>>>(hist, Boff, deg);
  int nb = (NN + 1023) / 1024;
  k_scan1<<<dim3(nb), dim3(256), 0, stream>>>(deg, incl, bsum);
  k_scan2<<<dim3(1), dim3(64), 0, stream>>>(bsum, boff, nb);
  k_scan3<<<dim3((NN + 255) / 256), dim3(256), 0, stream>>>(incl, boff, rowp);
  k_scatter2<<<dim3(NPART * NCHUNK), dim3(256), 0, stream>>>(srcp, dstp, rowp, Boff, srt);

  k_conv<<<dim3(384 + NN * 64 / 256 + 1), dim3(256), 0, stream>>>(W1, W2, Wt, x, bufA);

  // h lives in bufA across layers; z in bufB (row NN of both = zero sentinel)
  int mgrid = (NN + 63) / 64;  // 1563
  for (int l = 0; l < NL; ++l) {
    k_agg<<<dim3(NN / 4), dim3(256), 0, stream>>>(bufA, rowp, srt, eps, l, bufB);
    k_mlp3<<<dim3(mgrid), dim3(256), 0, stream>>>((const ushortT*)bufB,
                                                  Wt + (2 * l) * 16384, Wt + (2 * l + 1) * 16384,
                                                  b1 + l * 128, b2 + l * 128,
                                                  gam + l * 128, bet + l * 128,
                                                  rm + l * 128, rv + l * 128,
                                                  (ushortT*)bufA,
                                                  batch, pooled, (l == NL - 1) ? 1 : 0);
  }

  k_head<<<dim3(NG), dim3(128), 0, stream>>>(pooled, fc1w, fc1b, fc2w, fc2b, fc3w, fc3b, out);
}